// Round 3
// baseline (1229.362 us; speedup 1.0000x reference)
//
#include <hip/hip_runtime.h>
#include <hip/hip_bf16.h>
#include <stdint.h>

#define B_    128
#define F_    4
#define V_    2048
#define D_    4096
#define DW    64      // D/64 bit-words per (b,f) row
#define VW    32      // V/64 bit-words per d column
#define ITERS 20
#define NKT   16      // K tiles of 128 over V=2048

typedef _Float16 half8 __attribute__((ext_vector_type(8)));
typedef float   floatx4 __attribute__((ext_vector_type(4)));

// ------------------------------------------------------------------
// Pack sign bits: each thread handles 16 consecutive floats (4 float4
// loads) -> one u16 store.  Little-endian makes u16 writes == u64 bits.
// ------------------------------------------------------------------
__global__ __launch_bounds__(256) void k_pack(const float* __restrict__ x,
                                              uint16_t* __restrict__ bits16, int n16) {
    int t = blockIdx.x * blockDim.x + threadIdx.x;
    if (t >= n16) return;
    const float4* p = (const float4*)(x + (size_t)t * 16);
    unsigned m = 0;
    #pragma unroll
    for (int j = 0; j < 4; ++j) {
        float4 v = p[j];
        m |= (v.x < 0.0f ? 1u : 0u) << (4 * j + 0);
        m |= (v.y < 0.0f ? 1u : 0u) << (4 * j + 1);
        m |= (v.z < 0.0f ? 1u : 0u) << (4 * j + 2);
        m |= (v.w < 0.0f ? 1u : 0u) << (4 * j + 3);
    }
    bits16[t] = (uint16_t)m;
}

// ------------------------------------------------------------------
// Transpose cb_bits[f][v][dwords] -> cbT[f][d][vwords].
// ------------------------------------------------------------------
__global__ void k_packT(const uint64_t* __restrict__ cb_bits,
                        uint64_t* __restrict__ cbT) {
    int vw = blockIdx.x, dwg = blockIdx.y, f = blockIdx.z;
    int lane = threadIdx.x & 63;
    int dw = dwg * 4 + (threadIdx.x >> 6);
    uint64_t w = cb_bits[((size_t)f * V_ + vw * 64 + lane) * DW + dw];
    uint64_t r = 0;
    for (int d2 = 0; d2 < 64; ++d2) {
        uint64_t m = __ballot((unsigned)((w >> d2) & 1));
        if (lane == d2) r = m;
    }
    cbT[((size_t)f * D_ + dw * 64 + lane) * VW + vw] = r;
}

// ------------------------------------------------------------------
// nb[f][b][w] = in ^ e0^e1^e2^e3 ^ ef  (wave-uniform data for k_sim).
// ------------------------------------------------------------------
__global__ void k_nb(const uint64_t* __restrict__ in_bits,
                     const uint64_t* __restrict__ est_bits,
                     uint64_t* __restrict__ nb,
                     const int* __restrict__ flags, int iter) {
    if (iter > 0 && flags[iter - 1] == 0) return;
    int t = blockIdx.x * blockDim.x + threadIdx.x;   // f*B*DW total
    int w = t & 63, b = (t >> 6) & (B_ - 1), f = t >> 13;
    const uint64_t* e = est_bits + (size_t)b * F_ * DW;
    nb[t] = in_bits[(size_t)b * DW + w] ^ e[0 * DW + w] ^ e[1 * DW + w]
          ^ e[2 * DW + w] ^ e[3 * DW + w] ^ e[(size_t)f * DW + w];
}

// ------------------------------------------------------------------
// sim[b,f,v] = 2048 - popcount(nb ^ cb_row), exact fp16.
// nb rows are block-uniform -> scalar loads; NO LDS.  4 b per thread.
// grid (vt=8, bg=32, f=4) = 1024 blocks, block 256.
// ------------------------------------------------------------------
__global__ __launch_bounds__(256) void k_sim(
        const uint64_t* __restrict__ cb_bits,
        const uint64_t* __restrict__ nb,
        _Float16* __restrict__ simf,
        const int* __restrict__ flags, int iter) {
    if (iter > 0 && flags[iter - 1] == 0) return;
    int vt = blockIdx.x, bg = blockIdx.y, f = blockIdx.z;
    int tid = threadIdx.x;
    int v = vt * 256 + tid;
    const uint64_t* cbrow = cb_bits + ((size_t)f * V_ + v) * DW;
    const uint64_t* nbp = nb + ((size_t)f * B_ + bg * 4) * DW;
    int acc[4] = {2048, 2048, 2048, 2048};
    #pragma unroll
    for (int wc = 0; wc < 8; ++wc) {
        ulonglong2 c[4];
        #pragma unroll
        for (int j = 0; j < 4; ++j) c[j] = *(const ulonglong2*)&cbrow[wc * 8 + j * 2];
        #pragma unroll
        for (int bb = 0; bb < 4; ++bb) {
            const uint64_t* nrow = nbp + bb * DW + wc * 8;   // uniform -> s_load
            #pragma unroll
            for (int j = 0; j < 4; ++j) {
                acc[bb] -= __popcll(c[j].x ^ nrow[j * 2])
                         + __popcll(c[j].y ^ nrow[j * 2 + 1]);
            }
        }
    }
    #pragma unroll
    for (int bb = 0; bb < 4; ++bb)
        simf[((size_t)f * B_ + bg * 4 + bb) * V_ + v] = (_Float16)acc[bb];  // |acc|<=2048 exact
}

// ------------------------------------------------------------------
// C[b,d] = sum_v sim[b,v] * (+-1 from cbT bits); hardsign -> est_bits.
// BM=128 BN=64 BK=128; grid (nt=64, f=4) = 256 blocks, 256 thr.
// 4 waves, wave-tile 32m x 64n (wn=1: no A re-read across waves).
// B decode: 4 VALU per u32 via multiply-spread.
// ------------------------------------------------------------------
__global__ __launch_bounds__(256) void k_gemm(
        const _Float16* __restrict__ simf,
        const uint64_t* __restrict__ cbT,
        uint64_t* __restrict__ est_bits,
        int* __restrict__ flags, int iter) {
    if (iter > 0 && flags[iter - 1] == 0) return;
    int nt = blockIdx.x, f = blockIdx.y;
    int tid = threadIdx.x;
    int lane = tid & 63, wave = tid >> 6;
    int lrow = lane & 15, lq = lane >> 4;

    __shared__ __align__(16) uint64_t Bb[64 * VW];      // 16 KB bit panel
    __shared__ __align__(16) _Float16 As[128 * 128];    // 32 KB A tile
    __shared__ int bd;
    if (tid == 0) bd = 0;

    // preload B bit-panel: 64 d-rows x 32 vwords, swizzled 16B chunks
    const uint64_t* bsrc = cbT + ((size_t)f * D_ + nt * 64) * VW;
    #pragma unroll
    for (int p = 0; p < 4; ++p) {
        int chunk = p * 256 + tid;
        int dloc = chunk >> 4, cw = chunk & 15;
        ulonglong2 val = *(const ulonglong2*)&bsrc[dloc * VW + cw * 2];
        *(ulonglong2*)&Bb[dloc * VW + ((cw ^ (dloc & 15)) * 2)] = val;
    }

    const _Float16* Ab = simf + (size_t)f * B_ * V_;
    int arow = tid >> 4, acol = tid & 15;      // 16 rows x 16 chunks per pass
    half8 areg[8];
    #pragma unroll
    for (int p = 0; p < 8; ++p)
        areg[p] = *(const half8*)&Ab[(size_t)(p * 16 + arow) * V_ + acol * 8];

    floatx4 acc[2][4] = {};

    #pragma unroll 1
    for (int kt = 0; kt < NKT; ++kt) {
        __syncthreads();
        #pragma unroll
        for (int p = 0; p < 8; ++p)
            *(half8*)&As[(p * 16 + arow) * 128 + ((acol ^ arow) * 8)] = areg[p];
        if (kt + 1 < NKT) {
            #pragma unroll
            for (int p = 0; p < 8; ++p)
                areg[p] = *(const half8*)&Ab[(size_t)(p * 16 + arow) * V_ + (kt + 1) * 128 + acol * 8];
        }
        __syncthreads();

        ulonglong2 bw[4];
        #pragma unroll
        for (int nt2 = 0; nt2 < 4; ++nt2) {
            int dloc = nt2 * 16 + lrow;
            bw[nt2] = *(const ulonglong2*)&Bb[dloc * VW + ((kt ^ (dloc & 15)) * 2)];
        }
        #pragma unroll
        for (int ks = 0; ks < 4; ++ks) {
            half8 af[2];
            #pragma unroll
            for (int mt2 = 0; mt2 < 2; ++mt2) {
                int row = wave * 32 + mt2 * 16 + lrow;
                af[mt2] = *(const half8*)&As[row * 128 + (((ks * 4 + lq) ^ lrow) * 8)];
            }
            half8 bfrag[4];
            #pragma unroll
            for (int nt2 = 0; nt2 < 4; ++nt2) {
                uint64_t w = (ks < 2) ? bw[nt2].x : bw[nt2].y;
                uint32_t byte = (uint32_t)(w >> (((ks & 1) * 4 + lq) * 8)) & 0xFFu;
                union { uint32_t u[4]; half8 h; } bu;
                #pragma unroll
                for (int i = 0; i < 4; ++i)
                    bu.u[i] = 0x3C003C00u ^ ((((byte >> (2 * i)) & 3u) * 0x40008000u) & 0x80008000u);
                bfrag[nt2] = bu.h;
            }
            #pragma unroll
            for (int mt2 = 0; mt2 < 2; ++mt2)
                #pragma unroll
                for (int nt2 = 0; nt2 < 4; ++nt2)
                    acc[mt2][nt2] = __builtin_amdgcn_mfma_f32_16x16x32_f16(
                        af[mt2], bfrag[nt2], acc[mt2][nt2], 0, 0, 0);
        }
    }

    // epilogue: hardsign -> LDS bytes -> one u64 word per b-row
    __syncthreads();
    unsigned char* S = (unsigned char*)As;
    #pragma unroll
    for (int mt2 = 0; mt2 < 2; ++mt2)
        #pragma unroll
        for (int nt2 = 0; nt2 < 4; ++nt2)
            #pragma unroll
            for (int r = 0; r < 4; ++r) {
                int row = wave * 32 + mt2 * 16 + lq * 4 + r;   // C/D: row = quad*4+reg
                int col = nt2 * 16 + lrow;                     // col = lane&15
                S[row * 64 + col] = (acc[mt2][nt2][r] < 0.0f) ? 1 : 0;  // sign(0)=+1
            }
    __syncthreads();
    if (tid < 128) {
        const uint64_t* Sw = (const uint64_t*)S;
        uint64_t m = 0;
        #pragma unroll
        for (int j = 0; j < 8; ++j) {
            uint64_t w = Sw[tid * 8 + j];
            m |= ((w * 0x0102040810204080ull) >> 56) << (8 * j);
        }
        size_t widx = ((size_t)tid * F_ + f) * DW + nt;
        uint64_t old = est_bits[widx];
        est_bits[widx] = m;
        if (old != m) atomicOr(&bd, 1);
    }
    __syncthreads();
    if (tid == 0 && bd) atomicOr(&flags[iter], 1);
}

// ------------------------------------------------------------------
// argmax_v |sim|: key = (|2048-pc|<<11) | (2047-v), atomicMax.
// ------------------------------------------------------------------
__global__ __launch_bounds__(256) void k_argmax(
        const uint64_t* __restrict__ cb_bits,
        const uint64_t* __restrict__ est_bits,
        int* __restrict__ keys) {
    int vt = blockIdx.x, bg = blockIdx.y, f = blockIdx.z;
    int tid = threadIdx.x, lane = tid & 63;
    __shared__ __align__(16) uint64_t eb[16][DW];
    #pragma unroll
    for (int j = 0; j < 4; ++j) {
        int idx = tid + j * 256;
        int bl = idx >> 6, w = idx & 63;
        eb[bl][w] = est_bits[((size_t)(bg * 16 + bl) * F_ + f) * DW + w];
    }
    __syncthreads();
    int v = vt * 256 + tid;
    const uint64_t* cbrow = cb_bits + ((size_t)f * V_ + v) * DW;
    int pc[16];
    #pragma unroll
    for (int bl = 0; bl < 16; ++bl) pc[bl] = 0;
    for (int w = 0; w < DW; w += 2) {
        ulonglong2 c2 = *(const ulonglong2*)&cbrow[w];
        #pragma unroll
        for (int bl = 0; bl < 16; ++bl) {
            ulonglong2 e2 = *(const ulonglong2*)&eb[bl][w];
            pc[bl] += __popcll(e2.x ^ c2.x) + __popcll(e2.y ^ c2.y);
        }
    }
    int key[16];
    #pragma unroll
    for (int bl = 0; bl < 16; ++bl) {
        int m = 2048 - pc[bl]; if (m < 0) m = -m;
        key[bl] = (m << 11) | (2047 - v);
    }
    #pragma unroll
    for (int s = 1; s < 64; s <<= 1)
        #pragma unroll
        for (int bl = 0; bl < 16; ++bl) {
            int o = __shfl_xor(key[bl], s, 64);
            if (o > key[bl]) key[bl] = o;
        }
    if (lane == 0)
        for (int bl = 0; bl < 16; ++bl)
            atomicMax(&keys[(size_t)(bg * 16 + bl) * F_ + f], key[bl]);
}

__global__ void k_final(const int* __restrict__ keys, const int* __restrict__ flags,
                        int* __restrict__ out) {
    int tid = blockIdx.x * blockDim.x + threadIdx.x;
    if (tid < B_ * F_) out[tid] = 2047 - (keys[tid] & 0x7FF);
    if (tid == 0) {
        int k = ITERS - 1;
        for (int i = 0; i < ITERS; ++i) if (flags[i] == 0) { k = i; break; }
        out[B_ * F_] = k;
    }
}

// ------------------------------------------------------------------
extern "C" void kernel_launch(void* const* d_in, const int* in_sizes, int n_in,
                              void* d_out, int out_size, void* d_ws, size_t ws_size,
                              hipStream_t stream) {
    const float* inputs = (const float*)d_in[0];   // (B, D)
    const float* inite  = (const float*)d_in[1];   // (B, F, D)
    const float* cb     = (const float*)d_in[2];   // (F, V, D)
    int* out = (int*)d_out;                        // 512 outcome + 1 k

    char* ws = (char*)d_ws;
    uint64_t* cb_bits  = (uint64_t*)ws;  ws += (size_t)F_ * V_ * DW * 8;   // 4 MiB
    uint64_t* cbT_bits = (uint64_t*)ws;  ws += (size_t)F_ * D_ * VW * 8;   // 4 MiB
    uint64_t* est_bits = (uint64_t*)ws;  ws += (size_t)B_ * F_ * DW * 8;   // 256 KiB
    uint64_t* in_bits  = (uint64_t*)ws;  ws += (size_t)B_ * DW * 8;        // 64 KiB
    uint64_t* nb       = (uint64_t*)ws;  ws += (size_t)F_ * B_ * DW * 8;   // 256 KiB
    _Float16* simf     = (_Float16*)ws;  ws += (size_t)F_ * B_ * V_ * 2;   // 2 MiB
    int*      flags    = (int*)ws;       ws += 32 * 4;
    int*      keys     = (int*)ws;       ws += B_ * F_ * 4;

    hipMemsetAsync(flags, 0, (32 + B_ * F_) * sizeof(int), stream);
    k_pack<<<(F_ * V_ * D_) / 16 / 256, 256, 0, stream>>>(cb,     (uint16_t*)cb_bits,  F_ * V_ * D_ / 16);
    k_pack<<<(B_ * F_ * D_) / 16 / 256, 256, 0, stream>>>(inite,  (uint16_t*)est_bits, B_ * F_ * D_ / 16);
    k_pack<<<(B_ * D_) / 16 / 256,      256, 0, stream>>>(inputs, (uint16_t*)in_bits,  B_ * D_ / 16);
    k_packT<<<dim3(32, 16, 4), 256, 0, stream>>>(cb_bits, cbT_bits);

    for (int i = 0; i < ITERS; ++i) {
        k_nb<<<(F_ * B_ * DW) / 256, 256, 0, stream>>>(in_bits, est_bits, nb, flags, i);
        k_sim<<<dim3(8, 32, 4), 256, 0, stream>>>(cb_bits, nb, simf, flags, i);
        k_gemm<<<dim3(64, 4), 256, 0, stream>>>(simf, cbT_bits, est_bits, flags, i);
    }
    k_argmax<<<dim3(8, 8, 4), 256, 0, stream>>>(cb_bits, est_bits, keys);
    k_final<<<2, 256, 0, stream>>>(keys, flags, out);
}